// Round 2
// baseline (1273.957 us; speedup 1.0000x reference)
//
#include <hip/hip_runtime.h>
#include <hip/hip_bf16.h>

#define NN 30000
#define DIM 128
#define NT 6
#define NE 480000
#define NSLOT 1024
#define NSEG (NT*3*NSLOT)   // 18432
#define SEGCAP 128

__device__ __forceinline__ float lrelu(float x){ return x > 0.f ? x : 0.2f*x; }

__global__ void k_init(int* __restrict__ n2s, int* __restrict__ cnt){
    int i = blockIdx.x*blockDim.x + threadIdx.x;
    int stride = gridDim.x*blockDim.x;
    for (int j = i; j < NN; j += stride) n2s[j] = 1<<30;
    for (int j = i; j < NSEG; j += stride) cnt[j] = 0;
}

__global__ void k_slotmap(const int* __restrict__ s, int* __restrict__ n2s){
    int i = blockIdx.x*blockDim.x + threadIdx.x;
    if (i < NSLOT) atomicMin(&n2s[s[i]], i);
}

// h = X@W for one of {p,c} per blockIdx.y; att scalars folded into epilogue.
// 32 rows/block, only X staged in LDS (16KB) -> high occupancy.
__global__ __launch_bounds__(256, 4) void k_gemm_att(const float* __restrict__ X,
        const float* __restrict__ Wp, const float* __restrict__ Wc,
        const float* __restrict__ aspv, const float* __restrict__ adpv,
        const float* __restrict__ ascv, const float* __restrict__ adcv,
        float* __restrict__ hp, float* __restrict__ hc,
        float* __restrict__ asp, float* __restrict__ adp,
        float* __restrict__ asc, float* __restrict__ adc){
    __shared__ float Xs[32*DIM];
    int t = threadIdx.x;
    int m = blockIdx.y;
    const float* W    = m ? Wc   : Wp;
    const float* av_s = m ? ascv : aspv;
    const float* av_d = m ? adcv : adpv;
    float* h   = m ? hc  : hp;
    float* oas = m ? asc : asp;
    float* oad = m ? adc : adp;
    int row0 = blockIdx.x*32;
    for (int j = t; j < 32*DIM/4; j += 256){
        int r = row0 + (j>>5);
        float4 v = make_float4(0.f,0.f,0.f,0.f);
        if (r < NN) v = *(const float4*)&X[(size_t)r*DIM + (j&31)*4];
        *(float4*)&Xs[j*4] = v;
    }
    __syncthreads();
    int cg = t & 31, rg = t >> 5;
    int c4 = cg*4;
    float acc[4][4];
    #pragma unroll
    for (int a=0;a<4;a++){ acc[a][0]=0.f; acc[a][1]=0.f; acc[a][2]=0.f; acc[a][3]=0.f; }
    for (int k0=0;k0<DIM;k0+=4){
        float4 xr[4];
        #pragma unroll
        for (int ri=0;ri<4;ri++) xr[ri] = *(const float4*)&Xs[(rg*4+ri)*DIM + k0];
        #pragma unroll
        for (int kk=0;kk<4;kk++){
            float4 w = *(const float4*)&W[(k0+kk)*DIM + c4];
            #pragma unroll
            for (int ri=0;ri<4;ri++){
                float xv = (kk==0)?xr[ri].x:(kk==1)?xr[ri].y:(kk==2)?xr[ri].z:xr[ri].w;
                acc[ri][0] += xv*w.x; acc[ri][1] += xv*w.y;
                acc[ri][2] += xv*w.z; acc[ri][3] += xv*w.w;
            }
        }
    }
    float4 avs = *(const float4*)&av_s[c4];
    float4 avd = *(const float4*)&av_d[c4];
    #pragma unroll
    for (int ri=0;ri<4;ri++){
        int r = row0 + rg*4 + ri;
        float ds = acc[ri][0]*avs.x + acc[ri][1]*avs.y + acc[ri][2]*avs.z + acc[ri][3]*avs.w;
        float dd = acc[ri][0]*avd.x + acc[ri][1]*avd.y + acc[ri][2]*avd.z + acc[ri][3]*avd.w;
        #pragma unroll
        for (int off=16; off; off>>=1){
            ds += __shfl_xor(ds, off);
            dd += __shfl_xor(dd, off);
        }
        if (r < NN){
            *(float4*)&h[(size_t)r*DIM + c4] = make_float4(acc[ri][0],acc[ri][1],acc[ri][2],acc[ri][3]);
            if (cg == 0){ oas[r] = ds; oad[r] = dd; }
        }
    }
}

// one pass: match dst -> slot, atomic pos, write src into fixed-stride csr
__global__ __launch_bounds__(256) void k_build(const int* __restrict__ EI, const int* __restrict__ n2s,
        int* __restrict__ cnt, int* __restrict__ csr){
    const int Q = NE/4;          // 120000 int4 per row
    int total = NT*3*Q;          // 2,160,000
    for (int idx = blockIdx.x*blockDim.x + threadIdx.x; idx < total; idx += gridDim.x*blockDim.x){
        int tg = idx / Q; int e4 = idx - tg*Q;
        const int4* dstp = (const int4*)(EI + (size_t)(tg*2+1)*NE);
        int4 d = dstp[e4];
        int s0 = n2s[d.x], s1 = n2s[d.y], s2 = n2s[d.z], s3 = n2s[d.w];
        if (s0 < NSLOT || s1 < NSLOT || s2 < NSLOT || s3 < NSLOT){
            int4 sv = ((const int4*)(EI + (size_t)(tg*2)*NE))[e4];
            int base = tg*NSLOT;
            if (s0 < NSLOT){ int p = atomicAdd(&cnt[base+s0],1); if (p < SEGCAP) csr[(size_t)(base+s0)*SEGCAP+p] = sv.x; }
            if (s1 < NSLOT){ int p = atomicAdd(&cnt[base+s1],1); if (p < SEGCAP) csr[(size_t)(base+s1)*SEGCAP+p] = sv.y; }
            if (s2 < NSLOT){ int p = atomicAdd(&cnt[base+s2],1); if (p < SEGCAP) csr[(size_t)(base+s2)*SEGCAP+p] = sv.z; }
            if (s3 < NSLOT){ int p = atomicAdd(&cnt[base+s3],1); if (p < SEGCAP) csr[(size_t)(base+s3)*SEGCAP+p] = sv.w; }
        }
    }
}

// wave per (t, gat, slot) segment; plain stores to private buffers
__global__ __launch_bounds__(256, 4) void k_gat(const float* __restrict__ hp, const float* __restrict__ hc,
        const float* __restrict__ asp, const float* __restrict__ adp,
        const float* __restrict__ asc, const float* __restrict__ adc,
        const float* __restrict__ bp, const float* __restrict__ bc,
        const int* __restrict__ s, const int* __restrict__ cnt, const int* __restrict__ csr,
        float* __restrict__ bufP, float* __restrict__ bufC){
    int gw = (blockIdx.x*blockDim.x + threadIdx.x) >> 6;
    int lane = threadIdx.x & 63;
    if (gw >= NT*2*NSLOT) return;
    int slot = gw & (NSLOT-1);
    int tg2 = gw >> 10;
    int gat = tg2 & 1, t = tg2 >> 1;
    const float* h  = gat ? hc  : hp;
    const float* as = gat ? asc : asp;
    const float* ad = gat ? adc : adp;
    const float* b  = gat ? bc  : bp;
    int v = s[slot];
    int seg = (t*3+gat)*NSLOT + slot;
    int n = cnt[seg]; if (n > SEGCAP) n = SEGCAP;
    const int* lst = csr + (size_t)seg*SEGCAP;
    float adv = ad[v];
    float eself = lrelu(as[v] + adv);
    float m = eself;
    for (int j = lane; j < n; j += 64)
        m = fmaxf(m, lrelu(as[lst[j]] + adv));
    for (int off=32; off; off>>=1) m = fmaxf(m, __shfl_xor(m, off));
    float pself = __expf(eself - m);
    float denom = pself;
    float a0 = pself * h[(size_t)v*DIM + lane];
    float a1 = pself * h[(size_t)v*DIM + 64 + lane];
    for (int j = 0; j < n; j++){
        int src = lst[j];
        float p = __expf(lrelu(as[src] + adv) - m);
        denom += p;
        a0 += p * h[(size_t)src*DIM + lane];
        a1 += p * h[(size_t)src*DIM + 64 + lane];
    }
    float inv = 1.f/denom;
    float* ob = gat ? bufC : bufP;
    ob[(size_t)(t*NSLOT+slot)*DIM + lane]      = a0*inv + b[lane];
    ob[(size_t)(t*NSLOT+slot)*DIM + 64 + lane] = a1*inv + b[64+lane];
}

// wave per (t, slot): SAGE mean + two 128x128 matvecs, plain store
__global__ __launch_bounds__(256, 4) void k_sage(const float* __restrict__ X,
        const float* __restrict__ Wl, const float* __restrict__ Wr,
        const float* __restrict__ bl, const float* __restrict__ br,
        const int* __restrict__ s, const int* __restrict__ cnt, const int* __restrict__ csr,
        float* __restrict__ bufS){
    __shared__ float mean_s[4][DIM];
    __shared__ float xv_s[4][DIM];
    int gw = (blockIdx.x*blockDim.x + threadIdx.x) >> 6;
    int lane = threadIdx.x & 63;
    int wib = threadIdx.x >> 6;
    if (gw >= NT*NSLOT) return;
    int slot = gw & (NSLOT-1), t = gw >> 10;
    int v = s[slot];
    int seg = (t*3+2)*NSLOT + slot;
    int n = cnt[seg]; if (n > SEGCAP) n = SEGCAP;
    const int* lst = csr + (size_t)seg*SEGCAP;
    float m0 = 0.f, m1 = 0.f;
    for (int j = 0; j < n; j++){
        int src = lst[j];
        m0 += X[(size_t)src*DIM + lane];
        m1 += X[(size_t)src*DIM + 64 + lane];
    }
    float c = (float)n; if (c < 1.f) c = 1.f;
    float invc = 1.f/c;
    mean_s[wib][lane]    = m0*invc;
    mean_s[wib][64+lane] = m1*invc;
    xv_s[wib][lane]      = X[(size_t)v*DIM + lane];
    xv_s[wib][64+lane]   = X[(size_t)v*DIM + 64 + lane];
    __syncthreads();
    float a0 = bl[lane]    + br[lane];
    float a1 = bl[64+lane] + br[64+lane];
    for (int k=0;k<DIM;k++){
        float mv = mean_s[wib][k], xv = xv_s[wib][k];
        a0 += mv*Wl[k*DIM + lane]      + xv*Wr[k*DIM + lane];
        a1 += mv*Wl[k*DIM + 64 + lane] + xv*Wr[k*DIM + 64 + lane];
    }
    bufS[(size_t)(t*NSLOT+slot)*DIM + lane]      = a0;
    bufS[(size_t)(t*NSLOT+slot)*DIM + 64 + lane] = a1;
}

__global__ void k_gather(const int* __restrict__ s, const int* __restrict__ n2s,
                         const float* __restrict__ bufP, const float* __restrict__ bufC,
                         const float* __restrict__ bufS, float* __restrict__ out){
    int i = blockIdx.x*blockDim.x + threadIdx.x;
    if (i >= NT*NSLOT*DIM) return;
    int d = i & 127;
    int r = (i >> 7) & (NSLOT-1);
    int t = i >> 17;
    int rep = n2s[s[r]];
    size_t j = (size_t)(t*NSLOT + rep)*DIM + d;
    out[i] = (bufP[j] + bufC[j] + bufS[j]) * (1.f/3.f);
}

extern "C" void kernel_launch(void* const* d_in, const int* in_sizes, int n_in,
                              void* d_out, int out_size, void* d_ws, size_t ws_size,
                              hipStream_t stream) {
    const int*   s    = (const int*)d_in[0];
    const int*   EI   = (const int*)d_in[3];
    const float* X    = (const float*)d_in[4];
    const float* Wp   = (const float*)d_in[5];
    const float* aspv = (const float*)d_in[6];
    const float* adpv = (const float*)d_in[7];
    const float* bp   = (const float*)d_in[8];
    const float* Wc   = (const float*)d_in[9];
    const float* ascv = (const float*)d_in[10];
    const float* adcv = (const float*)d_in[11];
    const float* bc   = (const float*)d_in[12];
    const float* Wl   = (const float*)d_in[13];
    const float* bl   = (const float*)d_in[14];
    const float* Wr   = (const float*)d_in[15];
    const float* br   = (const float*)d_in[16];
    float* out = (float*)d_out;

    char* w = (char*)d_ws;
    float* hp  = (float*)w; w += (size_t)NN*DIM*4;
    float* hc  = (float*)w; w += (size_t)NN*DIM*4;
    float* asp = (float*)w; w += (size_t)NN*4;
    float* adp = (float*)w; w += (size_t)NN*4;
    float* asc = (float*)w; w += (size_t)NN*4;
    float* adc = (float*)w; w += (size_t)NN*4;
    int* n2s  = (int*)w; w += (size_t)NN*4;
    int* cnt  = (int*)w; w += (size_t)NSEG*4;
    int* csr  = (int*)w; w += (size_t)NSEG*SEGCAP*4;
    float* bufP = (float*)w; w += (size_t)NT*NSLOT*DIM*4;
    float* bufC = (float*)w; w += (size_t)NT*NSLOT*DIM*4;
    float* bufS = (float*)w; w += (size_t)NT*NSLOT*DIM*4;

    k_init   <<<256, 256, 0, stream>>>(n2s, cnt);
    k_slotmap<<<4, 256, 0, stream>>>(s, n2s);
    dim3 gg((NN+31)/32, 2);
    k_gemm_att<<<gg, 256, 0, stream>>>(X, Wp, Wc, aspv, adpv, ascv, adcv,
                                       hp, hc, asp, adp, asc, adc);
    k_build  <<<2048, 256, 0, stream>>>(EI, n2s, cnt, csr);
    k_gat    <<<NT*2*NSLOT/4, 256, 0, stream>>>(hp, hc, asp, adp, asc, adc, bp, bc, s, cnt, csr, bufP, bufC);
    k_sage   <<<NT*NSLOT/4, 256, 0, stream>>>(X, Wl, Wr, bl, br, s, cnt, csr, bufS);
    k_gather <<<NT*NSLOT*DIM/256, 256, 0, stream>>>(s, n2s, bufP, bufC, bufS, out);
}

// Round 3
// 184.614 us; speedup vs baseline: 6.9007x; 6.9007x over previous
//
#include <hip/hip_runtime.h>
#include <hip/hip_bf16.h>

#define NN 30000
#define DIM 128
#define NT 6
#define NE 480000
#define NSLOT 1024
#define NSEG (NT*3*NSLOT)   // 18432
#define SEGCAP 96
#define NBM ((NN+31)/32)    // 938

typedef __attribute__((ext_vector_type(8))) short bf16x8;
typedef __attribute__((ext_vector_type(4))) float f32x4;

__device__ __forceinline__ float lrelu(float x){ return x > 0.f ? x : 0.2f*x; }
__device__ __forceinline__ unsigned short f2b(float f){
    unsigned u = __float_as_uint(f);
    u = (u + 0x7FFFu + ((u>>16)&1u)) >> 16;
    return (unsigned short)u;
}
__device__ __forceinline__ float b2f(unsigned short b){
    return __uint_as_float(((unsigned)b)<<16);
}

__global__ void k_init(int* __restrict__ n2s, int* __restrict__ cnt,
                       unsigned* __restrict__ bm, float* __restrict__ comb){
    int i = blockIdx.x*blockDim.x + threadIdx.x;
    int stride = gridDim.x*blockDim.x;
    for (int j = i; j < NN; j += stride) n2s[j] = 1<<30;
    for (int j = i; j < NSEG; j += stride) cnt[j] = 0;
    for (int j = i; j < NBM; j += stride) bm[j] = 0u;
    for (int j = i; j < NT*NSLOT*DIM; j += stride) comb[j] = 0.f;
}

__global__ void k_slotmap(const int* __restrict__ s, int* __restrict__ n2s,
                          unsigned* __restrict__ bm){
    int i = blockIdx.x*blockDim.x + threadIdx.x;
    if (i < NSLOT){
        int v = s[i];
        atomicMin(&n2s[v], i);
        atomicOr(&bm[v>>5], 1u << (v&31));
    }
}

// per-matrix: wa_s = W@att_s, wa_d = W@att_d (f32), plus transposed bf16 W
__global__ void k_prep(const float* __restrict__ Wp, const float* __restrict__ Wc,
        const float* __restrict__ aspv, const float* __restrict__ adpv,
        const float* __restrict__ ascv, const float* __restrict__ adcv,
        float* __restrict__ wa, unsigned short* __restrict__ WTp,
        unsigned short* __restrict__ WTc){
    int m = blockIdx.x, t = threadIdx.x;
    const float* W   = m ? Wc   : Wp;
    const float* avs = m ? ascv : aspv;
    const float* avd = m ? adcv : adpv;
    unsigned short* WT = m ? WTc : WTp;
    float* wab = wa + m*2*DIM;
    if (t < DIM){
        float s = 0.f, d = 0.f;
        for (int n = 0; n < DIM; n++){
            float w = W[t*DIM + n];
            s += w*avs[n]; d += w*avd[n];
        }
        wab[t] = s; wab[DIM + t] = d;
    }
    for (int j = t; j < DIM*DIM; j += blockDim.x){
        int n = j >> 7, k = j & 127;
        WT[n*DIM + k] = f2b(W[k*DIM + n]);
    }
}

// wave per node: cast X row to bf16 + 4 attention scalars (f32 via wa)
__global__ __launch_bounds__(256) void k_cast(const float* __restrict__ X,
        const float* __restrict__ wa, unsigned* __restrict__ Xbf,
        float* __restrict__ asp, float* __restrict__ adp,
        float* __restrict__ asc, float* __restrict__ adc){
    int gw = (blockIdx.x*blockDim.x + threadIdx.x) >> 6;
    int lane = threadIdx.x & 63;
    if (gw >= NN) return;
    float2 x = *(const float2*)&X[(size_t)gw*DIM + lane*2];
    Xbf[(size_t)gw*(DIM/2) + lane] = (unsigned)f2b(x.x) | ((unsigned)f2b(x.y) << 16);
    float sp = x.x*wa[2*lane]     + x.y*wa[2*lane+1];
    float dp = x.x*wa[128+2*lane] + x.y*wa[128+2*lane+1];
    float sc = x.x*wa[256+2*lane] + x.y*wa[256+2*lane+1];
    float dc = x.x*wa[384+2*lane] + x.y*wa[384+2*lane+1];
    #pragma unroll
    for (int off = 32; off; off >>= 1){
        sp += __shfl_xor(sp, off); dp += __shfl_xor(dp, off);
        sc += __shfl_xor(sc, off); dc += __shfl_xor(dc, off);
    }
    if (lane == 0){ asp[gw] = sp; adp[gw] = dp; asc[gw] = sc; adc[gw] = dc; }
}

// MFMA GEMM: wave = 16 rows x 128 cols, both matrices; no LDS, no barriers.
__global__ __launch_bounds__(256) void k_gemm(const unsigned short* __restrict__ Xbf,
        const unsigned short* __restrict__ WTp, const unsigned short* __restrict__ WTc,
        float* __restrict__ hp, float* __restrict__ hc){
    int wid = threadIdx.x >> 6, lane = threadIdx.x & 63;
    int r0 = blockIdx.x*64 + wid*16;
    int arow = r0 + (lane & 15); if (arow > NN-1) arow = NN-1;
    int g = lane >> 4;
    bf16x8 A[4];
    #pragma unroll
    for (int ks = 0; ks < 4; ks++)
        A[ks] = *(const bf16x8*)&Xbf[(size_t)arow*DIM + ks*32 + g*8];
    int cl = lane & 15;
    #pragma unroll
    for (int ct = 0; ct < 8; ct++){
        f32x4 aP = {0.f,0.f,0.f,0.f}, aC = {0.f,0.f,0.f,0.f};
        int bcol = ct*16 + cl;
        #pragma unroll
        for (int ks = 0; ks < 4; ks++){
            bf16x8 bP = *(const bf16x8*)&WTp[bcol*DIM + ks*32 + g*8];
            bf16x8 bC = *(const bf16x8*)&WTc[bcol*DIM + ks*32 + g*8];
            aP = __builtin_amdgcn_mfma_f32_16x16x32_bf16(A[ks], bP, aP, 0, 0, 0);
            aC = __builtin_amdgcn_mfma_f32_16x16x32_bf16(A[ks], bC, aC, 0, 0, 0);
        }
        #pragma unroll
        for (int r = 0; r < 4; r++){
            int row = r0 + g*4 + r;
            if (row < NN){
                hp[(size_t)row*DIM + bcol] = aP[r];
                hc[(size_t)row*DIM + bcol] = aC[r];
            }
        }
    }
}

// bitmap-filtered single-pass CSR build
__global__ __launch_bounds__(256) void k_build(const int* __restrict__ EI,
        const unsigned* __restrict__ bm, const int* __restrict__ n2s,
        int* __restrict__ cnt, int* __restrict__ csr){
    const int Q = NE/4;
    int total = NT*3*Q;
    for (int idx = blockIdx.x*blockDim.x + threadIdx.x; idx < total; idx += gridDim.x*blockDim.x){
        int tg = idx / Q; int e4 = idx - tg*Q;
        int4 d = ((const int4*)(EI + (size_t)(tg*2+1)*NE))[e4];
        unsigned m0 = (bm[d.x>>5] >> (d.x&31)) & 1u;
        unsigned m1 = (bm[d.y>>5] >> (d.y&31)) & 1u;
        unsigned m2 = (bm[d.z>>5] >> (d.z&31)) & 1u;
        unsigned m3 = (bm[d.w>>5] >> (d.w&31)) & 1u;
        if (m0|m1|m2|m3){
            int4 sv = ((const int4*)(EI + (size_t)(tg*2)*NE))[e4];
            int base = tg*NSLOT;
            if (m0){ int sl = n2s[d.x]; int p = atomicAdd(&cnt[base+sl],1); if (p < SEGCAP) csr[(size_t)(base+sl)*SEGCAP+p] = sv.x; }
            if (m1){ int sl = n2s[d.y]; int p = atomicAdd(&cnt[base+sl],1); if (p < SEGCAP) csr[(size_t)(base+sl)*SEGCAP+p] = sv.y; }
            if (m2){ int sl = n2s[d.z]; int p = atomicAdd(&cnt[base+sl],1); if (p < SEGCAP) csr[(size_t)(base+sl)*SEGCAP+p] = sv.z; }
            if (m3){ int sl = n2s[d.w]; int p = atomicAdd(&cnt[base+sl],1); if (p < SEGCAP) csr[(size_t)(base+sl)*SEGCAP+p] = sv.w; }
        }
    }
}

// wave per (t, gat, slot) segment
__global__ __launch_bounds__(256) void k_gat(const float* __restrict__ hp, const float* __restrict__ hc,
        const float* __restrict__ asp, const float* __restrict__ adp,
        const float* __restrict__ asc, const float* __restrict__ adc,
        const float* __restrict__ bp, const float* __restrict__ bc,
        const int* __restrict__ s, const int* __restrict__ cnt, const int* __restrict__ csr,
        float* __restrict__ comb){
    int gw = (blockIdx.x*blockDim.x + threadIdx.x) >> 6;
    int lane = threadIdx.x & 63;
    if (gw >= NT*2*NSLOT) return;
    int slot = gw & (NSLOT-1);
    int tg2 = gw >> 10;
    int gat = tg2 & 1, t = tg2 >> 1;
    const float* h  = gat ? hc  : hp;
    const float* as = gat ? asc : asp;
    const float* ad = gat ? adc : adp;
    const float* b  = gat ? bc  : bp;
    int v = s[slot];
    int seg = (t*3+gat)*NSLOT + slot;
    int n = cnt[seg]; if (n > SEGCAP) n = SEGCAP;
    const int* lst = csr + (size_t)seg*SEGCAP;
    float adv = ad[v];
    float eself = lrelu(as[v] + adv);
    float m = eself;
    for (int j = lane; j < n; j += 64)
        m = fmaxf(m, lrelu(as[lst[j]] + adv));
    #pragma unroll
    for (int off = 32; off; off >>= 1) m = fmaxf(m, __shfl_xor(m, off));
    float pself = __expf(eself - m);
    float denom = pself;
    float a0 = pself * h[(size_t)v*DIM + lane];
    float a1 = pself * h[(size_t)v*DIM + 64 + lane];
    for (int j = 0; j < n; j++){
        int src = lst[j];
        float p = __expf(lrelu(as[src] + adv) - m);
        denom += p;
        a0 += p * h[(size_t)src*DIM + lane];
        a1 += p * h[(size_t)src*DIM + 64 + lane];
    }
    float inv = 1.f/denom;
    atomicAdd(&comb[(size_t)(t*NSLOT+slot)*DIM + lane],      (a0*inv + b[lane])    * (1.f/3.f));
    atomicAdd(&comb[(size_t)(t*NSLOT+slot)*DIM + 64 + lane], (a1*inv + b[64+lane]) * (1.f/3.f));
}

// wave per (t, slot): SAGE mean (bf16 X) + two 128x128 matvecs
__global__ __launch_bounds__(256) void k_sage(const unsigned* __restrict__ Xbf,
        const float* __restrict__ Wl, const float* __restrict__ Wr,
        const float* __restrict__ bl, const float* __restrict__ br,
        const int* __restrict__ s, const int* __restrict__ cnt, const int* __restrict__ csr,
        float* __restrict__ comb){
    __shared__ float mean_s[4][DIM];
    __shared__ float xv_s[4][DIM];
    int gw = (blockIdx.x*blockDim.x + threadIdx.x) >> 6;
    int lane = threadIdx.x & 63;
    int wib = threadIdx.x >> 6;
    if (gw >= NT*NSLOT) return;
    int slot = gw & (NSLOT-1), t = gw >> 10;
    int v = s[slot];
    int seg = (t*3+2)*NSLOT + slot;
    int n = cnt[seg]; if (n > SEGCAP) n = SEGCAP;
    const int* lst = csr + (size_t)seg*SEGCAP;
    float m0 = 0.f, m1 = 0.f;
    for (int j = 0; j < n; j++){
        unsigned pk = Xbf[(size_t)lst[j]*(DIM/2) + lane];
        m0 += b2f((unsigned short)(pk & 0xFFFF));
        m1 += b2f((unsigned short)(pk >> 16));
    }
    float c = (float)n; if (c < 1.f) c = 1.f;
    float invc = 1.f/c;
    mean_s[wib][2*lane]   = m0*invc;
    mean_s[wib][2*lane+1] = m1*invc;
    unsigned pv = Xbf[(size_t)v*(DIM/2) + lane];
    xv_s[wib][2*lane]   = b2f((unsigned short)(pv & 0xFFFF));
    xv_s[wib][2*lane+1] = b2f((unsigned short)(pv >> 16));
    __syncthreads();
    float a0 = bl[2*lane]   + br[2*lane];
    float a1 = bl[2*lane+1] + br[2*lane+1];
    for (int k = 0; k < DIM; k++){
        float mv = mean_s[wib][k], xv = xv_s[wib][k];
        float2 wl = *(const float2*)&Wl[k*DIM + 2*lane];
        float2 wr = *(const float2*)&Wr[k*DIM + 2*lane];
        a0 += mv*wl.x + xv*wr.x;
        a1 += mv*wl.y + xv*wr.y;
    }
    atomicAdd(&comb[(size_t)(t*NSLOT+slot)*DIM + 2*lane],   a0*(1.f/3.f));
    atomicAdd(&comb[(size_t)(t*NSLOT+slot)*DIM + 2*lane+1], a1*(1.f/3.f));
}

__global__ void k_gather(const int* __restrict__ s, const int* __restrict__ n2s,
                         const float* __restrict__ comb, float* __restrict__ out){
    int i = blockIdx.x*blockDim.x + threadIdx.x;
    if (i >= NT*NSLOT*DIM) return;
    int d = i & 127;
    int r = (i >> 7) & (NSLOT-1);
    int t = i >> 17;
    int rep = n2s[s[r]];
    out[i] = comb[(size_t)(t*NSLOT + rep)*DIM + d];
}

extern "C" void kernel_launch(void* const* d_in, const int* in_sizes, int n_in,
                              void* d_out, int out_size, void* d_ws, size_t ws_size,
                              hipStream_t stream) {
    const int*   s    = (const int*)d_in[0];
    const int*   EI   = (const int*)d_in[3];
    const float* X    = (const float*)d_in[4];
    const float* Wp   = (const float*)d_in[5];
    const float* aspv = (const float*)d_in[6];
    const float* adpv = (const float*)d_in[7];
    const float* bp   = (const float*)d_in[8];
    const float* Wc   = (const float*)d_in[9];
    const float* ascv = (const float*)d_in[10];
    const float* adcv = (const float*)d_in[11];
    const float* bc   = (const float*)d_in[12];
    const float* Wl   = (const float*)d_in[13];
    const float* bl   = (const float*)d_in[14];
    const float* Wr   = (const float*)d_in[15];
    const float* br   = (const float*)d_in[16];
    float* out = (float*)d_out;

    char* w = (char*)d_ws;
    float* hp  = (float*)w; w += (size_t)NN*DIM*4;
    float* hc  = (float*)w; w += (size_t)NN*DIM*4;
    unsigned* Xbf = (unsigned*)w; w += (size_t)NN*(DIM/2)*4;
    unsigned short* WTp = (unsigned short*)w; w += (size_t)DIM*DIM*2;
    unsigned short* WTc = (unsigned short*)w; w += (size_t)DIM*DIM*2;
    float* wa  = (float*)w; w += (size_t)4*DIM*4;
    float* asp = (float*)w; w += (size_t)NN*4;
    float* adp = (float*)w; w += (size_t)NN*4;
    float* asc = (float*)w; w += (size_t)NN*4;
    float* adc = (float*)w; w += (size_t)NN*4;
    int* n2s  = (int*)w; w += (size_t)NN*4;
    unsigned* bm = (unsigned*)w; w += (size_t)((NBM+3)&~3)*4;
    int* cnt  = (int*)w; w += (size_t)NSEG*4;
    int* csr  = (int*)w; w += (size_t)NSEG*SEGCAP*4;
    float* comb = (float*)w; w += (size_t)NT*NSLOT*DIM*4;

    k_init   <<<256, 256, 0, stream>>>(n2s, cnt, bm, comb);
    k_slotmap<<<4, 256, 0, stream>>>(s, n2s, bm);
    k_prep   <<<2, 256, 0, stream>>>(Wp, Wc, aspv, adpv, ascv, adcv, wa, WTp, WTc);
    k_cast   <<<(NN+3)/4, 256, 0, stream>>>(X, wa, Xbf, asp, adp, asc, adc);
    k_gemm   <<<(NN+63)/64, 256, 0, stream>>>((const unsigned short*)Xbf, WTp, WTc, hp, hc);
    k_build  <<<2048, 256, 0, stream>>>(EI, bm, n2s, cnt, csr);
    k_gat    <<<NT*2*NSLOT/4, 256, 0, stream>>>(hp, hc, asp, adp, asc, adc, bp, bc, s, cnt, csr, comb);
    k_sage   <<<NT*NSLOT/4, 256, 0, stream>>>(Xbf, Wl, Wr, bl, br, s, cnt, csr, comb);
    k_gather <<<NT*NSLOT*DIM/256, 256, 0, stream>>>(s, n2s, comb, out);
}

// Round 4
// 154.422 us; speedup vs baseline: 8.2498x; 1.1955x over previous
//
#include <hip/hip_runtime.h>
#include <hip/hip_bf16.h>

#define NN 30000
#define DIM 128
#define NT 6
#define NE 480000
#define NSLOT 1024
#define NSEG (NT*3*NSLOT)   // 18432
#define SEGCAP 96
#define NBM ((NN+31)/32)    // 938

typedef __attribute__((ext_vector_type(8))) short bf16x8;
typedef __attribute__((ext_vector_type(4))) float f32x4;

__device__ __forceinline__ float lrelu(float x){ return x > 0.f ? x : 0.2f*x; }
__device__ __forceinline__ unsigned short f2b(float f){
    unsigned u = __float_as_uint(f);
    u = (u + 0x7FFFu + ((u>>16)&1u)) >> 16;
    return (unsigned short)u;
}
__device__ __forceinline__ float b2f(unsigned short b){
    return __uint_as_float(((unsigned)b)<<16);
}

__global__ void k_init(int* __restrict__ n2s, int* __restrict__ cnt,
                       unsigned* __restrict__ bm, float* __restrict__ comb){
    int i = blockIdx.x*blockDim.x + threadIdx.x;
    int stride = gridDim.x*blockDim.x;
    for (int j = i; j < NN; j += stride) n2s[j] = 1<<30;
    for (int j = i; j < NSEG; j += stride) cnt[j] = 0;
    for (int j = i; j < NBM; j += stride) bm[j] = 0u;
    for (int j = i; j < NT*NSLOT*DIM; j += stride) comb[j] = 0.f;
}

__global__ void k_slotmap(const int* __restrict__ s, int* __restrict__ n2s,
                          unsigned* __restrict__ bm){
    int i = blockIdx.x*blockDim.x + threadIdx.x;
    if (i < NSLOT){
        int v = s[i];
        atomicMin(&n2s[v], i);
        atomicOr(&bm[v>>5], 1u << (v&31));
    }
}

// blocks 0..3 -> Wp,Wc,Wl,Wr: transposed bf16 WT[n][k]=W[k][n]; wa for 0,1
__global__ void k_prep(const float* __restrict__ Wp, const float* __restrict__ Wc,
        const float* __restrict__ Wl, const float* __restrict__ Wr,
        const float* __restrict__ aspv, const float* __restrict__ adpv,
        const float* __restrict__ ascv, const float* __restrict__ adcv,
        float* __restrict__ wa, unsigned short* __restrict__ WT4){
    int m = blockIdx.x, t = threadIdx.x;
    const float* W = (m==0) ? Wp : (m==1) ? Wc : (m==2) ? Wl : Wr;
    unsigned short* WT = WT4 + (size_t)m*DIM*DIM;
    if (m < 2 && t < DIM){
        const float* avs = m ? ascv : aspv;
        const float* avd = m ? adcv : adpv;
        float* wab = wa + m*2*DIM;
        float s = 0.f, d = 0.f;
        for (int n = 0; n < DIM; n++){
            float w = W[t*DIM + n];
            s += w*avs[n]; d += w*avd[n];
        }
        wab[t] = s; wab[DIM + t] = d;
    }
    for (int j = t; j < DIM*DIM; j += blockDim.x){
        int n = j >> 7, k = j & 127;
        WT[n*DIM + k] = f2b(W[k*DIM + n]);
    }
}

// wave per node: cast X row to bf16 + 4 attention scalars (f32 via wa)
__global__ __launch_bounds__(256) void k_cast(const float* __restrict__ X,
        const float* __restrict__ wa, unsigned* __restrict__ Xbf,
        float* __restrict__ asp, float* __restrict__ adp,
        float* __restrict__ asc, float* __restrict__ adc){
    int gw = (blockIdx.x*blockDim.x + threadIdx.x) >> 6;
    int lane = threadIdx.x & 63;
    if (gw >= NN) return;
    float2 x = *(const float2*)&X[(size_t)gw*DIM + lane*2];
    Xbf[(size_t)gw*(DIM/2) + lane] = (unsigned)f2b(x.x) | ((unsigned)f2b(x.y) << 16);
    float sp = x.x*wa[2*lane]     + x.y*wa[2*lane+1];
    float dp = x.x*wa[128+2*lane] + x.y*wa[128+2*lane+1];
    float sc = x.x*wa[256+2*lane] + x.y*wa[256+2*lane+1];
    float dc = x.x*wa[384+2*lane] + x.y*wa[384+2*lane+1];
    #pragma unroll
    for (int off = 32; off; off >>= 1){
        sp += __shfl_xor(sp, off); dp += __shfl_xor(dp, off);
        sc += __shfl_xor(sc, off); dc += __shfl_xor(dc, off);
    }
    if (lane == 0){ asp[gw] = sp; adp[gw] = dp; asc[gw] = sc; adc[gw] = dc; }
}

// copy the 1024 sampled rows of Xbf into a dense block for the Wr GEMM
__global__ __launch_bounds__(256) void k_xcopy(const int* __restrict__ s,
        const unsigned* __restrict__ Xbf, unsigned* __restrict__ xselfb){
    int gw = (blockIdx.x*blockDim.x + threadIdx.x) >> 6;
    int lane = threadIdx.x & 63;
    if (gw >= NSLOT) return;
    xselfb[(size_t)gw*(DIM/2) + lane] = Xbf[(size_t)s[gw]*(DIM/2) + lane];
}

// MFMA GEMM: wave = 16 rows x 128 cols, both P and C matrices; bf16 out.
__global__ __launch_bounds__(256) void k_gemm(const unsigned short* __restrict__ Xbf,
        const unsigned short* __restrict__ WT4,
        unsigned short* __restrict__ hpb, unsigned short* __restrict__ hcb){
    const unsigned short* WTp = WT4;
    const unsigned short* WTc = WT4 + DIM*DIM;
    int wid = threadIdx.x >> 6, lane = threadIdx.x & 63;
    int r0 = blockIdx.x*64 + wid*16;
    int arow = r0 + (lane & 15); if (arow > NN-1) arow = NN-1;
    int g = lane >> 4;
    bf16x8 A[4];
    #pragma unroll
    for (int ks = 0; ks < 4; ks++)
        A[ks] = *(const bf16x8*)&Xbf[(size_t)arow*DIM + ks*32 + g*8];
    int cl = lane & 15;
    #pragma unroll
    for (int ct = 0; ct < 8; ct++){
        f32x4 aP = {0.f,0.f,0.f,0.f}, aC = {0.f,0.f,0.f,0.f};
        int bcol = ct*16 + cl;
        #pragma unroll
        for (int ks = 0; ks < 4; ks++){
            bf16x8 bP = *(const bf16x8*)&WTp[bcol*DIM + ks*32 + g*8];
            bf16x8 bC = *(const bf16x8*)&WTc[bcol*DIM + ks*32 + g*8];
            aP = __builtin_amdgcn_mfma_f32_16x16x32_bf16(A[ks], bP, aP, 0, 0, 0);
            aC = __builtin_amdgcn_mfma_f32_16x16x32_bf16(A[ks], bC, aC, 0, 0, 0);
        }
        #pragma unroll
        for (int r = 0; r < 4; r++){
            int row = r0 + g*4 + r;
            if (row < NN){
                hpb[(size_t)row*DIM + bcol] = f2b(aP[r]);
                hcb[(size_t)row*DIM + bcol] = f2b(aC[r]);
            }
        }
    }
}

// bitmap-filtered single-pass CSR build
__global__ __launch_bounds__(256) void k_build(const int* __restrict__ EI,
        const unsigned* __restrict__ bm, const int* __restrict__ n2s,
        int* __restrict__ cnt, int* __restrict__ csr){
    const int Q = NE/4;
    int total = NT*3*Q;
    for (int idx = blockIdx.x*blockDim.x + threadIdx.x; idx < total; idx += gridDim.x*blockDim.x){
        int tg = idx / Q; int e4 = idx - tg*Q;
        int4 d = ((const int4*)(EI + (size_t)(tg*2+1)*NE))[e4];
        unsigned m0 = (bm[d.x>>5] >> (d.x&31)) & 1u;
        unsigned m1 = (bm[d.y>>5] >> (d.y&31)) & 1u;
        unsigned m2 = (bm[d.z>>5] >> (d.z&31)) & 1u;
        unsigned m3 = (bm[d.w>>5] >> (d.w&31)) & 1u;
        if (m0|m1|m2|m3){
            int4 sv = ((const int4*)(EI + (size_t)(tg*2)*NE))[e4];
            int base = tg*NSLOT;
            if (m0){ int sl = n2s[d.x]; int p = atomicAdd(&cnt[base+sl],1); if (p < SEGCAP) csr[(size_t)(base+sl)*SEGCAP+p] = sv.x; }
            if (m1){ int sl = n2s[d.y]; int p = atomicAdd(&cnt[base+sl],1); if (p < SEGCAP) csr[(size_t)(base+sl)*SEGCAP+p] = sv.y; }
            if (m2){ int sl = n2s[d.z]; int p = atomicAdd(&cnt[base+sl],1); if (p < SEGCAP) csr[(size_t)(base+sl)*SEGCAP+p] = sv.z; }
            if (m3){ int sl = n2s[d.w]; int p = atomicAdd(&cnt[base+sl],1); if (p < SEGCAP) csr[(size_t)(base+sl)*SEGCAP+p] = sv.w; }
        }
    }
}

// wave per (t, gat, slot) segment; bf16 h, lane handles dims 2*lane,2*lane+1
__global__ __launch_bounds__(256) void k_gat(const unsigned* __restrict__ hpb, const unsigned* __restrict__ hcb,
        const float* __restrict__ asp, const float* __restrict__ adp,
        const float* __restrict__ asc, const float* __restrict__ adc,
        const float* __restrict__ bp, const float* __restrict__ bc,
        const int* __restrict__ s, const int* __restrict__ cnt, const int* __restrict__ csr,
        float* __restrict__ comb){
    int gw = (blockIdx.x*blockDim.x + threadIdx.x) >> 6;
    int lane = threadIdx.x & 63;
    if (gw >= NT*2*NSLOT) return;
    int slot = gw & (NSLOT-1);
    int tg2 = gw >> 10;
    int gat = tg2 & 1, t = tg2 >> 1;
    const unsigned* h = gat ? hcb : hpb;
    const float* as = gat ? asc : asp;
    const float* ad = gat ? adc : adp;
    const float* b  = gat ? bc  : bp;
    int v = s[slot];
    int seg = (t*3+gat)*NSLOT + slot;
    int n = cnt[seg]; if (n > SEGCAP) n = SEGCAP;
    const int* lst = csr + (size_t)seg*SEGCAP;
    float adv = ad[v];
    float eself = lrelu(as[v] + adv);
    float m = eself;
    for (int j = lane; j < n; j += 64)
        m = fmaxf(m, lrelu(as[lst[j]] + adv));
    #pragma unroll
    for (int off = 32; off; off >>= 1) m = fmaxf(m, __shfl_xor(m, off));
    float pself = __expf(eself - m);
    float denom = pself;
    unsigned pkv = h[(size_t)v*(DIM/2) + lane];
    float a0 = pself * b2f((unsigned short)(pkv & 0xFFFF));
    float a1 = pself * b2f((unsigned short)(pkv >> 16));
    for (int j = 0; j < n; j++){
        int src = lst[j];
        float p = __expf(lrelu(as[src] + adv) - m);
        denom += p;
        unsigned pk = h[(size_t)src*(DIM/2) + lane];
        a0 += p * b2f((unsigned short)(pk & 0xFFFF));
        a1 += p * b2f((unsigned short)(pk >> 16));
    }
    float inv = 1.f/denom;
    atomicAdd(&comb[(size_t)(t*NSLOT+slot)*DIM + 2*lane],   (a0*inv + b[2*lane])   * (1.f/3.f));
    atomicAdd(&comb[(size_t)(t*NSLOT+slot)*DIM + 2*lane+1], (a1*inv + b[2*lane+1]) * (1.f/3.f));
}

// wave per (t,slot): bf16 neighbor mean
__global__ __launch_bounds__(256) void k_smean(const unsigned* __restrict__ Xbf,
        const int* __restrict__ cnt, const int* __restrict__ csr,
        unsigned* __restrict__ meanb){
    int gw = (blockIdx.x*blockDim.x + threadIdx.x) >> 6;
    int lane = threadIdx.x & 63;
    if (gw >= NT*NSLOT) return;
    int slot = gw & (NSLOT-1), t = gw >> 10;
    int seg = (t*3+2)*NSLOT + slot;
    int n = cnt[seg]; if (n > SEGCAP) n = SEGCAP;
    const int* lst = csr + (size_t)seg*SEGCAP;
    float m0 = 0.f, m1 = 0.f;
    for (int j = 0; j < n; j++){
        unsigned pk = Xbf[(size_t)lst[j]*(DIM/2) + lane];
        m0 += b2f((unsigned short)(pk & 0xFFFF));
        m1 += b2f((unsigned short)(pk >> 16));
    }
    float c = (float)n; if (c < 1.f) c = 1.f;
    float invc = 1.f/c;
    meanb[(size_t)gw*(DIM/2) + lane] =
        (unsigned)f2b(m0*invc) | ((unsigned)f2b(m1*invc) << 16);
}

// blocks 0..95: meanb@WlT -> mWl [6144][128]; blocks 96..111: xselfb@WrT -> xWr [1024][128]
__global__ __launch_bounds__(256) void k_sgemm(const unsigned short* __restrict__ meanb,
        const unsigned short* __restrict__ xselfb, const unsigned short* __restrict__ WT4,
        float* __restrict__ mWl, float* __restrict__ xWr){
    int task = (blockIdx.x >= 96);
    int blk  = task ? (blockIdx.x - 96) : blockIdx.x;
    const unsigned short* A  = task ? xselfb : meanb;
    const unsigned short* WT = WT4 + (size_t)(task ? 3 : 2)*DIM*DIM;
    float* out = task ? xWr : mWl;
    int rows = task ? NSLOT : NT*NSLOT;
    int wid = threadIdx.x >> 6, lane = threadIdx.x & 63;
    int r0 = blk*64 + wid*16;
    int arow = r0 + (lane & 15); if (arow > rows-1) arow = rows-1;
    int g = lane >> 4;
    bf16x8 Af[4];
    #pragma unroll
    for (int ks = 0; ks < 4; ks++)
        Af[ks] = *(const bf16x8*)&A[(size_t)arow*DIM + ks*32 + g*8];
    int cl = lane & 15;
    #pragma unroll
    for (int ct = 0; ct < 8; ct++){
        f32x4 acc = {0.f,0.f,0.f,0.f};
        int bcol = ct*16 + cl;
        #pragma unroll
        for (int ks = 0; ks < 4; ks++){
            bf16x8 bF = *(const bf16x8*)&WT[bcol*DIM + ks*32 + g*8];
            acc = __builtin_amdgcn_mfma_f32_16x16x32_bf16(Af[ks], bF, acc, 0, 0, 0);
        }
        #pragma unroll
        for (int r = 0; r < 4; r++){
            int row = r0 + g*4 + r;
            if (row < rows) out[(size_t)row*DIM + bcol] = acc[r];
        }
    }
}

__global__ void k_gather(const int* __restrict__ s, const int* __restrict__ n2s,
                         const float* __restrict__ comb, const float* __restrict__ mWl,
                         const float* __restrict__ xWr,
                         const float* __restrict__ bl, const float* __restrict__ br,
                         float* __restrict__ out){
    int i = blockIdx.x*blockDim.x + threadIdx.x;
    if (i >= NT*NSLOT*DIM) return;
    int d = i & 127;
    int r = (i >> 7) & (NSLOT-1);
    int t = i >> 17;
    int rep = n2s[s[r]];
    size_t j = (size_t)(t*NSLOT + rep)*DIM + d;
    out[i] = comb[j] + (mWl[j] + xWr[(size_t)rep*DIM + d] + bl[d] + br[d]) * (1.f/3.f);
}

extern "C" void kernel_launch(void* const* d_in, const int* in_sizes, int n_in,
                              void* d_out, int out_size, void* d_ws, size_t ws_size,
                              hipStream_t stream) {
    const int*   s    = (const int*)d_in[0];
    const int*   EI   = (const int*)d_in[3];
    const float* X    = (const float*)d_in[4];
    const float* Wp   = (const float*)d_in[5];
    const float* aspv = (const float*)d_in[6];
    const float* adpv = (const float*)d_in[7];
    const float* bp   = (const float*)d_in[8];
    const float* Wc   = (const float*)d_in[9];
    const float* ascv = (const float*)d_in[10];
    const float* adcv = (const float*)d_in[11];
    const float* bc   = (const float*)d_in[12];
    const float* Wl   = (const float*)d_in[13];
    const float* bl   = (const float*)d_in[14];
    const float* Wr   = (const float*)d_in[15];
    const float* br   = (const float*)d_in[16];
    float* out = (float*)d_out;

    char* w = (char*)d_ws;
    unsigned short* hpb = (unsigned short*)w; w += (size_t)NN*DIM*2;
    unsigned short* hcb = (unsigned short*)w; w += (size_t)NN*DIM*2;
    unsigned* Xbf = (unsigned*)w; w += (size_t)NN*(DIM/2)*4;
    unsigned short* WT4 = (unsigned short*)w; w += (size_t)4*DIM*DIM*2;
    float* wa  = (float*)w; w += (size_t)4*DIM*4;
    float* asp = (float*)w; w += (size_t)NN*4;
    float* adp = (float*)w; w += (size_t)NN*4;
    float* asc = (float*)w; w += (size_t)NN*4;
    float* adc = (float*)w; w += (size_t)NN*4;
    int* n2s  = (int*)w; w += (size_t)NN*4;
    unsigned* bm = (unsigned*)w; w += (size_t)((NBM+3)&~3)*4;
    int* cnt  = (int*)w; w += (size_t)NSEG*4;
    int* csr  = (int*)w; w += (size_t)NSEG*SEGCAP*4;
    float* comb = (float*)w; w += (size_t)NT*NSLOT*DIM*4;
    unsigned* meanb = (unsigned*)w; w += (size_t)NT*NSLOT*(DIM/2)*4;
    unsigned* xselfb = (unsigned*)w; w += (size_t)NSLOT*(DIM/2)*4;
    float* mWl = (float*)w; w += (size_t)NT*NSLOT*DIM*4;
    float* xWr = (float*)w; w += (size_t)NSLOT*DIM*4;

    k_init   <<<256, 256, 0, stream>>>(n2s, cnt, bm, comb);
    k_slotmap<<<4, 256, 0, stream>>>(s, n2s, bm);
    k_prep   <<<4, 256, 0, stream>>>(Wp, Wc, Wl, Wr, aspv, adpv, ascv, adcv, wa, WT4);
    k_cast   <<<(NN+3)/4, 256, 0, stream>>>(X, wa, Xbf, asp, adp, asc, adc);
    k_xcopy  <<<NSLOT/4, 256, 0, stream>>>(s, Xbf, xselfb);
    k_gemm   <<<(NN+63)/64, 256, 0, stream>>>((const unsigned short*)Xbf, WT4, hpb, hcb);
    k_build  <<<2048, 256, 0, stream>>>(EI, bm, n2s, cnt, csr);
    k_gat    <<<NT*2*NSLOT/4, 256, 0, stream>>>((const unsigned*)hpb, (const unsigned*)hcb,
                                                asp, adp, asc, adc, bp, bc, s, cnt, csr, comb);
    k_smean  <<<NT*NSLOT/4, 256, 0, stream>>>(Xbf, cnt, csr, meanb);
    k_sgemm  <<<112, 256, 0, stream>>>((const unsigned short*)meanb, (const unsigned short*)xselfb,
                                       WT4, mWl, xWr);
    k_gather <<<NT*NSLOT*DIM/256, 256, 0, stream>>>(s, n2s, comb, mWl, xWr, bl, br, out);
}

// Round 5
// 150.019 us; speedup vs baseline: 8.4920x; 1.0294x over previous
//
#include <hip/hip_runtime.h>
#include <hip/hip_bf16.h>

#define NN 30000
#define DIM 128
#define NT 6
#define NE 480000
#define NSLOT 1024
#define NSEG (NT*3*NSLOT)   // 18432
#define SEGCAP 96
#define NBM ((NN+31)/32)    // 938

typedef __attribute__((ext_vector_type(8))) short bf16x8;
typedef __attribute__((ext_vector_type(4))) float f32x4;

__device__ __forceinline__ float lrelu(float x){ return x > 0.f ? x : 0.2f*x; }
__device__ __forceinline__ unsigned short f2b(float f){
    unsigned u = __float_as_uint(f);
    u = (u + 0x7FFFu + ((u>>16)&1u)) >> 16;
    return (unsigned short)u;
}
__device__ __forceinline__ float b2f(unsigned short b){
    return __uint_as_float(((unsigned)b)<<16);
}

__global__ void k_init(int* __restrict__ n2s, int* __restrict__ cnt,
                       unsigned* __restrict__ bm){
    int i = blockIdx.x*blockDim.x + threadIdx.x;
    int stride = gridDim.x*blockDim.x;
    for (int j = i; j < NN; j += stride) n2s[j] = 1<<30;
    for (int j = i; j < NSEG; j += stride) cnt[j] = 0;
    for (int j = i; j < NBM; j += stride) bm[j] = 0u;
}

__global__ void k_slotmap(const int* __restrict__ s, int* __restrict__ n2s,
                          unsigned* __restrict__ bm){
    int i = blockIdx.x*blockDim.x + threadIdx.x;
    if (i < NSLOT){
        int v = s[i];
        atomicMin(&n2s[v], i);
        atomicOr(&bm[v>>5], 1u << (v&31));
    }
}

// blocks 0..3 -> Wp,Wc,Wl,Wr: transposed bf16 WT[n][k]=W[k][n]; wa for 0,1
__global__ void k_prep(const float* __restrict__ Wp, const float* __restrict__ Wc,
        const float* __restrict__ Wl, const float* __restrict__ Wr,
        const float* __restrict__ aspv, const float* __restrict__ adpv,
        const float* __restrict__ ascv, const float* __restrict__ adcv,
        float* __restrict__ wa, unsigned short* __restrict__ WT4){
    int m = blockIdx.x, t = threadIdx.x;
    const float* W = (m==0) ? Wp : (m==1) ? Wc : (m==2) ? Wl : Wr;
    unsigned short* WT = WT4 + (size_t)m*DIM*DIM;
    if (m < 2 && t < DIM){
        const float* avs = m ? ascv : aspv;
        const float* avd = m ? adcv : adpv;
        float* wab = wa + m*2*DIM;
        float s = 0.f, d = 0.f;
        for (int n = 0; n < DIM; n++){
            float w = W[t*DIM + n];
            s += w*avs[n]; d += w*avd[n];
        }
        wab[t] = s; wab[DIM + t] = d;
    }
    for (int j = t; j < DIM*DIM; j += blockDim.x){
        int n = j >> 7, k = j & 127;
        WT[n*DIM + k] = f2b(W[k*DIM + n]);
    }
}

// wave per node: cast X row to bf16 + 4 attention scalars (f32 via wa)
__global__ __launch_bounds__(256) void k_cast(const float* __restrict__ X,
        const float* __restrict__ wa, unsigned* __restrict__ Xbf,
        float* __restrict__ asp, float* __restrict__ adp,
        float* __restrict__ asc, float* __restrict__ adc){
    int gw = (blockIdx.x*blockDim.x + threadIdx.x) >> 6;
    int lane = threadIdx.x & 63;
    if (gw >= NN) return;
    float2 x = *(const float2*)&X[(size_t)gw*DIM + lane*2];
    Xbf[(size_t)gw*(DIM/2) + lane] = (unsigned)f2b(x.x) | ((unsigned)f2b(x.y) << 16);
    float sp = x.x*wa[2*lane]     + x.y*wa[2*lane+1];
    float dp = x.x*wa[128+2*lane] + x.y*wa[128+2*lane+1];
    float sc = x.x*wa[256+2*lane] + x.y*wa[256+2*lane+1];
    float dc = x.x*wa[384+2*lane] + x.y*wa[384+2*lane+1];
    #pragma unroll
    for (int off = 32; off; off >>= 1){
        sp += __shfl_xor(sp, off); dp += __shfl_xor(dp, off);
        sc += __shfl_xor(sc, off); dc += __shfl_xor(dc, off);
    }
    if (lane == 0){ asp[gw] = sp; adp[gw] = dp; asc[gw] = sc; adc[gw] = dc; }
}

// copy the 1024 sampled rows of Xbf into a dense block for the Wr GEMM
__global__ __launch_bounds__(256) void k_xcopy(const int* __restrict__ s,
        const unsigned* __restrict__ Xbf, unsigned* __restrict__ xselfb){
    int gw = (blockIdx.x*blockDim.x + threadIdx.x) >> 6;
    int lane = threadIdx.x & 63;
    if (gw >= NSLOT) return;
    xselfb[(size_t)gw*(DIM/2) + lane] = Xbf[(size_t)s[gw]*(DIM/2) + lane];
}

// MFMA GEMM: wave = 16 rows x 128 cols, both P and C matrices; bf16 out.
__global__ __launch_bounds__(256) void k_gemm(const unsigned short* __restrict__ Xbf,
        const unsigned short* __restrict__ WT4,
        unsigned short* __restrict__ hpb, unsigned short* __restrict__ hcb){
    const unsigned short* WTp = WT4;
    const unsigned short* WTc = WT4 + DIM*DIM;
    int wid = threadIdx.x >> 6, lane = threadIdx.x & 63;
    int r0 = blockIdx.x*64 + wid*16;
    int arow = r0 + (lane & 15); if (arow > NN-1) arow = NN-1;
    int g = lane >> 4;
    bf16x8 A[4];
    #pragma unroll
    for (int ks = 0; ks < 4; ks++)
        A[ks] = *(const bf16x8*)&Xbf[(size_t)arow*DIM + ks*32 + g*8];
    int cl = lane & 15;
    #pragma unroll
    for (int ct = 0; ct < 8; ct++){
        f32x4 aP = {0.f,0.f,0.f,0.f}, aC = {0.f,0.f,0.f,0.f};
        int bcol = ct*16 + cl;
        #pragma unroll
        for (int ks = 0; ks < 4; ks++){
            bf16x8 bP = *(const bf16x8*)&WTp[bcol*DIM + ks*32 + g*8];
            bf16x8 bC = *(const bf16x8*)&WTc[bcol*DIM + ks*32 + g*8];
            aP = __builtin_amdgcn_mfma_f32_16x16x32_bf16(A[ks], bP, aP, 0, 0, 0);
            aC = __builtin_amdgcn_mfma_f32_16x16x32_bf16(A[ks], bC, aC, 0, 0, 0);
        }
        #pragma unroll
        for (int r = 0; r < 4; r++){
            int row = r0 + g*4 + r;
            if (row < NN){
                hpb[(size_t)row*DIM + bcol] = f2b(aP[r]);
                hcb[(size_t)row*DIM + bcol] = f2b(aC[r]);
            }
        }
    }
}

// bitmap-filtered single-pass CSR build; bitmap staged in LDS
__global__ __launch_bounds__(256) void k_build(const int* __restrict__ EI,
        const unsigned* __restrict__ bm, const int* __restrict__ n2s,
        int* __restrict__ cnt, int* __restrict__ csr){
    __shared__ unsigned bms[NBM];
    for (int j = threadIdx.x; j < NBM; j += 256) bms[j] = bm[j];
    __syncthreads();
    const int Q = NE/4;
    int total = NT*3*Q;
    for (int idx = blockIdx.x*blockDim.x + threadIdx.x; idx < total; idx += gridDim.x*blockDim.x){
        int tg = idx / Q; int e4 = idx - tg*Q;
        int4 d = ((const int4*)(EI + (size_t)(tg*2+1)*NE))[e4];
        unsigned m0 = (bms[d.x>>5] >> (d.x&31)) & 1u;
        unsigned m1 = (bms[d.y>>5] >> (d.y&31)) & 1u;
        unsigned m2 = (bms[d.z>>5] >> (d.z&31)) & 1u;
        unsigned m3 = (bms[d.w>>5] >> (d.w&31)) & 1u;
        if (m0|m1|m2|m3){
            int4 sv = ((const int4*)(EI + (size_t)(tg*2)*NE))[e4];
            int base = tg*NSLOT;
            if (m0){ int sl = n2s[d.x]; int p = atomicAdd(&cnt[base+sl],1); if (p < SEGCAP) csr[(size_t)(base+sl)*SEGCAP+p] = sv.x; }
            if (m1){ int sl = n2s[d.y]; int p = atomicAdd(&cnt[base+sl],1); if (p < SEGCAP) csr[(size_t)(base+sl)*SEGCAP+p] = sv.y; }
            if (m2){ int sl = n2s[d.z]; int p = atomicAdd(&cnt[base+sl],1); if (p < SEGCAP) csr[(size_t)(base+sl)*SEGCAP+p] = sv.z; }
            if (m3){ int sl = n2s[d.w]; int p = atomicAdd(&cnt[base+sl],1); if (p < SEGCAP) csr[(size_t)(base+sl)*SEGCAP+p] = sv.w; }
        }
    }
}

// wave per (t, gat, slot) segment; bf16 h; plain stores to bufP/bufC
__global__ __launch_bounds__(256) void k_gat(const unsigned* __restrict__ hpb, const unsigned* __restrict__ hcb,
        const float* __restrict__ asp, const float* __restrict__ adp,
        const float* __restrict__ asc, const float* __restrict__ adc,
        const float* __restrict__ bp, const float* __restrict__ bc,
        const int* __restrict__ s, const int* __restrict__ cnt, const int* __restrict__ csr,
        float* __restrict__ bufP, float* __restrict__ bufC){
    int gw = (blockIdx.x*blockDim.x + threadIdx.x) >> 6;
    int lane = threadIdx.x & 63;
    if (gw >= NT*2*NSLOT) return;
    int slot = gw & (NSLOT-1);
    int tg2 = gw >> 10;
    int gat = tg2 & 1, t = tg2 >> 1;
    const unsigned* h = gat ? hcb : hpb;
    const float* as = gat ? asc : asp;
    const float* ad = gat ? adc : adp;
    const float* b  = gat ? bc  : bp;
    int v = s[slot];
    int seg = (t*3+gat)*NSLOT + slot;
    int n = cnt[seg]; if (n > SEGCAP) n = SEGCAP;
    const int* lst = csr + (size_t)seg*SEGCAP;
    float adv = ad[v];
    float eself = lrelu(as[v] + adv);
    float m = eself;
    for (int j = lane; j < n; j += 64)
        m = fmaxf(m, lrelu(as[lst[j]] + adv));
    #pragma unroll
    for (int off = 32; off; off >>= 1) m = fmaxf(m, __shfl_xor(m, off));
    float pself = __expf(eself - m);
    float denom = pself;
    unsigned pkv = h[(size_t)v*(DIM/2) + lane];
    float a0 = pself * b2f((unsigned short)(pkv & 0xFFFF));
    float a1 = pself * b2f((unsigned short)(pkv >> 16));
    for (int j = 0; j < n; j++){
        int src = lst[j];
        float p = __expf(lrelu(as[src] + adv) - m);
        denom += p;
        unsigned pk = h[(size_t)src*(DIM/2) + lane];
        a0 += p * b2f((unsigned short)(pk & 0xFFFF));
        a1 += p * b2f((unsigned short)(pk >> 16));
    }
    float inv = 1.f/denom;
    float* ob = gat ? bufC : bufP;
    ob[(size_t)(t*NSLOT+slot)*DIM + 2*lane]   = a0*inv + b[2*lane];
    ob[(size_t)(t*NSLOT+slot)*DIM + 2*lane+1] = a1*inv + b[2*lane+1];
}

// wave per (t,slot): bf16 neighbor mean
__global__ __launch_bounds__(256) void k_smean(const unsigned* __restrict__ Xbf,
        const int* __restrict__ cnt, const int* __restrict__ csr,
        unsigned* __restrict__ meanb){
    int gw = (blockIdx.x*blockDim.x + threadIdx.x) >> 6;
    int lane = threadIdx.x & 63;
    if (gw >= NT*NSLOT) return;
    int slot = gw & (NSLOT-1), t = gw >> 10;
    int seg = (t*3+2)*NSLOT + slot;
    int n = cnt[seg]; if (n > SEGCAP) n = SEGCAP;
    const int* lst = csr + (size_t)seg*SEGCAP;
    float m0 = 0.f, m1 = 0.f;
    for (int j = 0; j < n; j++){
        unsigned pk = Xbf[(size_t)lst[j]*(DIM/2) + lane];
        m0 += b2f((unsigned short)(pk & 0xFFFF));
        m1 += b2f((unsigned short)(pk >> 16));
    }
    float c = (float)n; if (c < 1.f) c = 1.f;
    float invc = 1.f/c;
    meanb[(size_t)gw*(DIM/2) + lane] =
        (unsigned)f2b(m0*invc) | ((unsigned)f2b(m1*invc) << 16);
}

// blocks 0..95: meanb@WlT -> mWl [6144][128]; blocks 96..111: xselfb@WrT -> xWr [1024][128]
__global__ __launch_bounds__(256) void k_sgemm(const unsigned short* __restrict__ meanb,
        const unsigned short* __restrict__ xselfb, const unsigned short* __restrict__ WT4,
        float* __restrict__ mWl, float* __restrict__ xWr){
    int task = (blockIdx.x >= 96);
    int blk  = task ? (blockIdx.x - 96) : blockIdx.x;
    const unsigned short* A  = task ? xselfb : meanb;
    const unsigned short* WT = WT4 + (size_t)(task ? 3 : 2)*DIM*DIM;
    float* out = task ? xWr : mWl;
    int rows = task ? NSLOT : NT*NSLOT;
    int wid = threadIdx.x >> 6, lane = threadIdx.x & 63;
    int r0 = blk*64 + wid*16;
    int arow = r0 + (lane & 15); if (arow > rows-1) arow = rows-1;
    int g = lane >> 4;
    bf16x8 Af[4];
    #pragma unroll
    for (int ks = 0; ks < 4; ks++)
        Af[ks] = *(const bf16x8*)&A[(size_t)arow*DIM + ks*32 + g*8];
    int cl = lane & 15;
    #pragma unroll
    for (int ct = 0; ct < 8; ct++){
        f32x4 acc = {0.f,0.f,0.f,0.f};
        int bcol = ct*16 + cl;
        #pragma unroll
        for (int ks = 0; ks < 4; ks++){
            bf16x8 bF = *(const bf16x8*)&WT[bcol*DIM + ks*32 + g*8];
            acc = __builtin_amdgcn_mfma_f32_16x16x32_bf16(Af[ks], bF, acc, 0, 0, 0);
        }
        #pragma unroll
        for (int r = 0; r < 4; r++){
            int row = r0 + g*4 + r;
            if (row < rows) out[(size_t)row*DIM + bcol] = acc[r];
        }
    }
}

__global__ void k_gather(const int* __restrict__ s, const int* __restrict__ n2s,
                         const float* __restrict__ bufP, const float* __restrict__ bufC,
                         const float* __restrict__ mWl, const float* __restrict__ xWr,
                         const float* __restrict__ bl, const float* __restrict__ br,
                         float* __restrict__ out){
    int i = blockIdx.x*blockDim.x + threadIdx.x;
    if (i >= NT*NSLOT*DIM) return;
    int d = i & 127;
    int r = (i >> 7) & (NSLOT-1);
    int t = i >> 17;
    int rep = n2s[s[r]];
    size_t j = (size_t)(t*NSLOT + rep)*DIM + d;
    out[i] = (bufP[j] + bufC[j] + mWl[j] + xWr[(size_t)rep*DIM + d] + bl[d] + br[d]) * (1.f/3.f);
}

extern "C" void kernel_launch(void* const* d_in, const int* in_sizes, int n_in,
                              void* d_out, int out_size, void* d_ws, size_t ws_size,
                              hipStream_t stream) {
    const int*   s    = (const int*)d_in[0];
    const int*   EI   = (const int*)d_in[3];
    const float* X    = (const float*)d_in[4];
    const float* Wp   = (const float*)d_in[5];
    const float* aspv = (const float*)d_in[6];
    const float* adpv = (const float*)d_in[7];
    const float* bp   = (const float*)d_in[8];
    const float* Wc   = (const float*)d_in[9];
    const float* ascv = (const float*)d_in[10];
    const float* adcv = (const float*)d_in[11];
    const float* bc   = (const float*)d_in[12];
    const float* Wl   = (const float*)d_in[13];
    const float* bl   = (const float*)d_in[14];
    const float* Wr   = (const float*)d_in[15];
    const float* br   = (const float*)d_in[16];
    float* out = (float*)d_out;

    char* w = (char*)d_ws;
    unsigned short* hpb = (unsigned short*)w; w += (size_t)NN*DIM*2;
    unsigned short* hcb = (unsigned short*)w; w += (size_t)NN*DIM*2;
    unsigned* Xbf = (unsigned*)w; w += (size_t)NN*(DIM/2)*4;
    unsigned short* WT4 = (unsigned short*)w; w += (size_t)4*DIM*DIM*2;
    float* wa  = (float*)w; w += (size_t)4*DIM*4;
    float* asp = (float*)w; w += (size_t)NN*4;
    float* adp = (float*)w; w += (size_t)NN*4;
    float* asc = (float*)w; w += (size_t)NN*4;
    float* adc = (float*)w; w += (size_t)NN*4;
    int* n2s  = (int*)w; w += (size_t)NN*4;
    unsigned* bm = (unsigned*)w; w += (size_t)((NBM+3)&~3)*4;
    int* cnt  = (int*)w; w += (size_t)NSEG*4;
    int* csr  = (int*)w; w += (size_t)NSEG*SEGCAP*4;
    float* bufP = (float*)w; w += (size_t)NT*NSLOT*DIM*4;
    float* bufC = (float*)w; w += (size_t)NT*NSLOT*DIM*4;
    unsigned* meanb = (unsigned*)w; w += (size_t)NT*NSLOT*(DIM/2)*4;
    unsigned* xselfb = (unsigned*)w; w += (size_t)NSLOT*(DIM/2)*4;
    float* mWl = (float*)w; w += (size_t)NT*NSLOT*DIM*4;
    float* xWr = (float*)w; w += (size_t)NSLOT*DIM*4;

    k_init   <<<128, 256, 0, stream>>>(n2s, cnt, bm);
    k_slotmap<<<4, 256, 0, stream>>>(s, n2s, bm);
    k_prep   <<<4, 256, 0, stream>>>(Wp, Wc, Wl, Wr, aspv, adpv, ascv, adcv, wa, WT4);
    k_cast   <<<(NN+3)/4, 256, 0, stream>>>(X, wa, Xbf, asp, adp, asc, adc);
    k_xcopy  <<<NSLOT/4, 256, 0, stream>>>(s, Xbf, xselfb);
    k_gemm   <<<(NN+63)/64, 256, 0, stream>>>((const unsigned short*)Xbf, WT4, hpb, hcb);
    k_build  <<<2048, 256, 0, stream>>>(EI, bm, n2s, cnt, csr);
    k_gat    <<<NT*2*NSLOT/4, 256, 0, stream>>>((const unsigned*)hpb, (const unsigned*)hcb,
                                                asp, adp, asc, adc, bp, bc, s, cnt, csr, bufP, bufC);
    k_smean  <<<NT*NSLOT/4, 256, 0, stream>>>(Xbf, cnt, csr, meanb);
    k_sgemm  <<<112, 256, 0, stream>>>((const unsigned short*)meanb, (const unsigned short*)xselfb,
                                       WT4, mWl, xWr);
    k_gather <<<NT*NSLOT*DIM/256, 256, 0, stream>>>(s, n2s, bufP, bufC, mWl, xWr, bl, br, out);
}